// Round 2
// baseline (562.859 us; speedup 1.0000x reference)
//
#include <hip/hip_runtime.h>

#define IN_C   16
#define OUT_C  16
#define COEF_M 11
#define PLANE4 4096    // 128*128/4 float4s per plane
#define WSIZE  3328
#define I0     2816    // IN_C*OUT_C*COEF_M
#define I1     3072    // I0 + IN_C*OUT_C

__device__ __forceinline__ float4 f4_mul(float4 a, float4 b) {
    return make_float4(a.x*b.x, a.y*b.y, a.z*b.z, a.w*b.w);
}
__device__ __forceinline__ float4 f4_fma(float4 a, float4 b, float4 c) {
    return make_float4(fmaf(a.x,b.x,c.x), fmaf(a.y,b.y,c.y),
                       fmaf(a.z,b.z,c.z), fmaf(a.w,b.w,c.w));
}
__device__ __forceinline__ float4 f4_add(float4 a, float4 b) {
    return make_float4(a.x+b.x, a.y+b.y, a.z+b.z, a.w+b.w);
}

// grid = 512 blocks: 128 pixel-groups (256 px each) x 4 o-quads.
// block = 256 threads = 4 waves; wave g handles input channels i in {4g..4g+3}.
// Each lane processes 4 consecutive pixels via float4 (16 B/lane, 1 KB/wave-load).
__global__ __launch_bounds__(256, 2) void kan_kernel(
    const float* __restrict__ x, const float* __restrict__ w,
    float* __restrict__ out)
{
    const int tid = threadIdx.x;
    const int l   = tid & 63;         // lane within wave
    const int g   = tid >> 6;         // i-group / wave id 0..3
    const int pg  = blockIdx.x >> 2;  // pixel-group 0..127
    const int oq  = blockIdx.x & 3;   // o-quad 0..3
    const int o_base = oq * 4;

    const int p4 = pg * 64 + l;       // float4-pixel index 0..8191
    const int b  = p4 >> 12;          // PLANE4 = 2^12; groups never straddle b
    const int hw4 = p4 & (PLANE4 - 1);

    const float4* wb4 = (const float4*)w + (size_t)b * WSIZE * PLANE4 + hw4;
    const float4* xb4 = (const float4*)x + (size_t)b * IN_C  * PLANE4 + hw4;

    float4 acc[4];
    #pragma unroll
    for (int o = 0; o < 4; ++o) acc[o] = make_float4(0.f, 0.f, 0.f, 0.f);

    #pragma unroll
    for (int ii = 0; ii < 4; ++ii) {
        const int i = g * 4 + ii;
        const float4 xv = xb4[(size_t)i * PLANE4];

        // Cox-de Boor K=3, knots t_j = -1.75 + 0.25*j, j=0..14 (componentwise over 4 px)
        float4 bp[14];
        #pragma unroll
        for (int j = 0; j < 14; ++j) {
            const float tj  = -1.75f + 0.25f * j;
            const float tj1 = tj + 0.25f;
            bp[j] = make_float4(
                (xv.x >= tj && xv.x < tj1) ? 1.f : 0.f,
                (xv.y >= tj && xv.y < tj1) ? 1.f : 0.f,
                (xv.z >= tj && xv.z < tj1) ? 1.f : 0.f,
                (xv.w >= tj && xv.w < tj1) ? 1.f : 0.f);
        }
        #pragma unroll
        for (int p = 1; p <= 3; ++p) {
            const float inv = 1.0f / (0.25f * (float)p);
            #pragma unroll
            for (int j = 0; j < 14 - p; ++j) {
                const float tj = -1.75f + 0.25f * j;
                const float tr = tj + 0.25f * (float)(p + 1);
                float4 left  = make_float4((xv.x - tj)*inv, (xv.y - tj)*inv,
                                           (xv.z - tj)*inv, (xv.w - tj)*inv);
                float4 right = make_float4((tr - xv.x)*inv, (tr - xv.y)*inv,
                                           (tr - xv.z)*inv, (tr - xv.w)*inv);
                bp[j] = f4_fma(left, bp[j], f4_mul(right, bp[j + 1]));
            }
        }

        const float4 sx = make_float4(
            xv.x / (1.f + __expf(-xv.x)), xv.y / (1.f + __expf(-xv.y)),
            xv.z / (1.f + __expf(-xv.z)), xv.w / (1.f + __expf(-xv.w)));

        #pragma unroll
        for (int o = 0; o < 4; ++o) {
            const int og = o_base + o;
            const float4* c = wb4 + (size_t)(i * (OUT_C * COEF_M) + og * COEF_M) * PLANE4;
            float4 sp = make_float4(0.f, 0.f, 0.f, 0.f);
            #pragma unroll
            for (int m = 0; m < COEF_M; ++m)
                sp = f4_fma(c[(size_t)m * PLANE4], bp[m], sp);
            const float4 uwv = wb4[(size_t)(I0 + i * OUT_C + og) * PLANE4];
            const float4 rwv = wb4[(size_t)(I1 + i * OUT_C + og) * PLANE4];
            acc[o] = f4_fma(uwv, sp, f4_fma(rwv, sx, acc[o]));
        }
    }

    // reduce partials across the 4 i-group waves via LDS.
    // layout [wave][lane][o(+pad)] of float4: lane stride 80 B -> each 8-lane
    // cycle covers all 32 banks exactly once (conflict-free b128).
    __shared__ float4 red[4][64][5];
    #pragma unroll
    for (int o = 0; o < 4; ++o) red[g][l][o] = acc[o];
    __syncthreads();

    // wave g now owns output channel o_base + g: sum over the 4 i-groups
    float4 s = f4_add(f4_add(red[0][l][g], red[1][l][g]),
                      f4_add(red[2][l][g], red[3][l][g]));
    float4* out4 = (float4*)out;
    out4[(size_t)b * (OUT_C * PLANE4) + (size_t)(o_base + g) * PLANE4 + hw4] = s;
}

extern "C" void kernel_launch(void* const* d_in, const int* in_sizes, int n_in,
                              void* d_out, int out_size, void* d_ws, size_t ws_size,
                              hipStream_t stream) {
    const float* x = (const float*)d_in[0];   // (2,16,128,128) fp32
    const float* w = (const float*)d_in[1];   // (2,3328,128,128) fp32
    float* out = (float*)d_out;               // (2,16,128,128) fp32

    kan_kernel<<<dim3(512), dim3(256), 0, stream>>>(x, w, out);
}